// Round 9
// baseline (299.156 us; speedup 1.0000x reference)
//
#include <hip/hip_runtime.h>
#include <hip/hip_bf16.h>
#include <stdint.h>

#define N_NODES 100000
#define N_EDGES 1600000
#define CH 128
#define N_REL 8
#define N_PAD 100096            // N_NODES rounded up to multiple of 128
#define N_KEYS (N_NODES * N_REL)

#define NBKT 782                // N_PAD / 128 buckets (= bin/fused grid)
#define NCHUNK 782              // edge chunks (one per prep block)
#define CHUNK_E 2048            // edges per chunk (256 thr x 8)
#define CELL_CAP 20             // per-(chunk,bucket) cap; Poisson lam=2.62 ->
                                // P(>20) ~ 8e-13/cell, ~5e-7 overall
#define NSLOT (NBKT * CELL_CAP) // 15640 slots per chunk
#define PERM_LDS_CAP 4096       // per-bucket edges ~2046 +- 45 -> 45-sigma margin

using frag_ab = __attribute__((ext_vector_type(8))) short;  // 8 bf16
using frag_cd = __attribute__((ext_vector_type(4))) float;  // 4 fp32

__device__ __forceinline__ short f2bs(float f) {
    union { __hip_bfloat16 h; short s; } u;
    u.h = __float2bfloat16(f);
    return u.s;
}

__device__ __forceinline__ uint32_t pack2bf(float a, float b) {
    union { __hip_bfloat16 h; unsigned short s; } ua, ub;
    ua.h = __float2bfloat16(a); ub.h = __float2bfloat16(b);
    return (uint32_t)ua.s | ((uint32_t)ub.s << 16);
}

__device__ __forceinline__ float bf_lo(uint32_t u) { return __uint_as_float(u << 16); }
__device__ __forceinline__ float bf_hi(uint32_t u) { return __uint_as_float(u & 0xffff0000u); }

// ======================= prep: LDS-staged chunk binning =======================
// R9: exactly NCHUNK blocks (R8 allocated this kernel's 62.5KB LDS across a
// 6250-block grid, strangling the co-resident xconv at 8 waves/CU -- xconv now
// lives in bin_kernel). No sentinel init: validity comes from lens[], cells
// past lens are garbage and bin masks them. uint4 write-out = full-line stores.
// Entry: src<<10 | (dst&127)<<3 | rel. Zero global atomics.

__global__ __launch_bounds__(256)
void prep_kernel(const int* __restrict__ ei, const int* __restrict__ et,
                 uint32_t* __restrict__ ents, int* __restrict__ lens,
                 const float* __restrict__ root, const float* __restrict__ W,
                 short* __restrict__ Bsw) {
    __shared__ uint32_t cell[NSLOT];   // 62.5 KB, deliberately uninitialized
    __shared__ int cur[NBKT];
    const int tid = threadIdx.x;
    const int c = blockIdx.x;
    const int g = blockIdx.x * 256 + tid;

    // --- bconv rides on blocks 0..71 (no LDS use) ---
    if (g < 9 * 2048) {
        int chunk = g >> 11, entry = g & 2047;
        int m16 = entry & 15, ct = (entry >> 4) & 7, quad = (entry >> 7) & 3, ks = entry >> 9;
        const float* src = (chunk == 0) ? root : W + (size_t)(chunk - 1) * CH * CH;
        int col = ct * 16 + m16, kb = ks * 32 + quad * 8;
        frag_ab f;
#pragma unroll
        for (int j = 0; j < 8; ++j) f[j] = f2bs(src[(size_t)(kb + j) * CH + col]);
        *(frag_ab*)(Bsw + (size_t)g * 8) = f;
    }

    for (int i = tid; i < NBKT; i += 256) cur[i] = 0;
    __syncthreads();
#pragma unroll
    for (int j = 0; j < 8; ++j) {
        const int e = c * CHUNK_E + j * 256 + tid;   // coalesced ei/et reads
        if (e < N_EDGES) {
            const int dst = ei[N_EDGES + e];
            const int src = ei[e];
            const int r = et[e];
            const int b = dst >> 7;
            const int pos = atomicAdd(&cur[b], 1);   // LDS atomic: cycles
            if (pos < CELL_CAP)
                cell[b * CELL_CAP + pos] =
                    ((uint32_t)src << 10) | ((uint32_t)(dst & 127) << 3) | (uint32_t)r;
        }
    }
    __syncthreads();
    for (int i = tid; i < NBKT; i += 256) {
        int n = cur[i];
        lens[(size_t)c * NBKT + i] = (n > CELL_CAP) ? CELL_CAP : n;
    }
    {   // linear full-line write-out (garbage past lens is fine, bin masks it)
        const uint4* cs = (const uint4*)cell;
        uint4* dg = (uint4*)(ents + (size_t)c * NSLOT);
        for (int i = tid; i < NSLOT / 4; i += 256) dg[i] = cs[i];
    }
}

// ======================= bin: one block per bucket (+xconv ride-along) =======================
// Reads its OWN bucket's 782 cells (each cell read by exactly one block),
// ballot-compacts valid entries to LDS, then hist/scan/scatter -> global perm
// + local ends. xconv (x fp32 -> bf16, 77MB streaming) rides along up front:
// this kernel's LDS is small (high occupancy) and its binning phases leave HBM
// idle, so the conversion hides under them (R4-measured co-scheduling).

__global__ __launch_bounds__(512)
void bin_kernel(const uint32_t* __restrict__ ents, const int* __restrict__ lens,
                int* __restrict__ perm_g, int* __restrict__ ends_g,
                const float* __restrict__ x, short* __restrict__ xb) {
    __shared__ uint32_t stage[PERM_LDS_CAP];   // 16 KB compact entries
    __shared__ int hist[1024];
    __shared__ int cursor[1024];
    __shared__ int shl[512];
    __shared__ int lens_l[NCHUNK];
    __shared__ int ncomp;
    const int tid = threadIdx.x;
    const int lane = tid & 63;
    const int b = blockIdx.x;

    // --- xconv grid-stride (4 iterations/thread across the 782x512 grid) ---
    {
        const int nst = NBKT * 512;
        const float4* xp = (const float4*)x;
        for (int gi = b * 512 + tid; gi < N_NODES * CH / 8; gi += nst) {
            float4 a = xp[(size_t)gi * 2], bb = xp[(size_t)gi * 2 + 1];
            frag_ab f;
            f[0] = f2bs(a.x); f[1] = f2bs(a.y); f[2] = f2bs(a.z); f[3] = f2bs(a.w);
            f[4] = f2bs(bb.x); f[5] = f2bs(bb.y); f[6] = f2bs(bb.z); f[7] = f2bs(bb.w);
            *(frag_ab*)(xb + (size_t)gi * 8) = f;
        }
    }

    for (int i = tid; i < NCHUNK; i += 512) lens_l[i] = lens[(size_t)i * NBKT + b];
    hist[tid] = 0; hist[tid + 512] = 0;
    if (tid == 0) ncomp = 0;
    __syncthreads();
    for (int j = tid; j < NCHUNK * CELL_CAP; j += 512) {
        const int c = j / CELL_CAP, i = j - c * CELL_CAP;
        const bool hit = (i < lens_l[c]);
        uint32_t v = 0;
        if (hit) v = ents[(size_t)c * NSLOT + b * CELL_CAP + i];
        const unsigned long long m = __ballot(hit);
        if (m) {
            const int leader = __ffsll((long long)m) - 1;
            int base = 0;
            if (lane == leader) base = atomicAdd(&ncomp, __popcll(m));
            base = __shfl(base, leader);
            if (hit) {
                const int pos = base + __popcll(m & ((1ULL << lane) - 1ULL));
                if (pos < PERM_LDS_CAP) stage[pos] = v;
            }
        }
    }
    __syncthreads();
    int n = ncomp; if (n > PERM_LDS_CAP) n = PERM_LDS_CAP;
    for (int i = tid; i < n; i += 512) atomicAdd(&hist[stage[i] & 1023], 1);
    __syncthreads();
    const int h0 = hist[2 * tid], h1 = hist[2 * tid + 1];
    const int s2 = h0 + h1;
    shl[tid] = s2;
    __syncthreads();
    for (int st = 1; st < 512; st <<= 1) {   // Hillis-Steele inclusive over pair-sums
        int u = (tid >= st) ? shl[tid - st] : 0;
        __syncthreads();
        shl[tid] += u;
        __syncthreads();
    }
    const int excl = shl[tid] - s2;
    cursor[2 * tid]     = excl;
    cursor[2 * tid + 1] = excl + h0;
    {   // local (0-based) segment ends, clamped so fused LDS reads are in-bounds
        int e1 = excl + h0, e2 = excl + h0 + h1;
        ends_g[(size_t)b * 1024 + 2 * tid]     = (e1 > PERM_LDS_CAP) ? PERM_LDS_CAP : e1;
        ends_g[(size_t)b * 1024 + 2 * tid + 1] = (e2 > PERM_LDS_CAP) ? PERM_LDS_CAP : e2;
    }
    __syncthreads();
    for (int i = tid; i < n; i += 512) {
        const uint32_t v = stage[i];
        const int pos = atomicAdd(&cursor[v & 1023], 1);
        if (pos < PERM_LDS_CAP) perm_g[(size_t)b * PERM_LDS_CAP + pos] = (int)(v >> 10);
    }
}

// ======================= FUSED aggregate + GEMM (unchanged, 131us @ R8) =======================
#define ACC_U4(U, B)                                            \
    do {                                                        \
        a[(B)+0] += bf_lo((U).x); a[(B)+1] += bf_hi((U).x);     \
        a[(B)+2] += bf_lo((U).y); a[(B)+3] += bf_hi((U).y);     \
        a[(B)+4] += bf_lo((U).z); a[(B)+5] += bf_hi((U).z);     \
        a[(B)+6] += bf_lo((U).w); a[(B)+7] += bf_hi((U).w);     \
    } while (0)

__global__ __launch_bounds__(512, 4)
void rgcn_fused(const int* __restrict__ ends_g, const int* __restrict__ perm_g,
                const short* __restrict__ xb, const short* __restrict__ Bsw,
                const float* __restrict__ bias, float* __restrict__ out) {
    __shared__ short Ash[128 * 128];        // 32 KB swizzled A-tile
    __shared__ int perm_lds[PERM_LDS_CAP];  // 16 KB
    __shared__ int lends[1025];             // local ends; lends[0] = 0
    const int tid = threadIdx.x;
    const int wave = tid >> 6, lane = tid & 63;
    const int m16 = lane & 15, quad = lane >> 4;
    const int wm = wave >> 2, wn = wave & 3;     // wave tile: 64 rows x 32 cols
    const int b = blockIdx.x;
    const long B0 = (long)b * 128;

    if (tid == 0) { lends[0] = 0; perm_lds[0] = 0; }
    for (int i = tid; i < 1024; i += 512) lends[1 + i] = ends_g[(size_t)b * 1024 + i];
    __syncthreads();
    const int nperm = lends[1024];
    for (int i = tid; i < nperm; i += 512) perm_lds[i] = perm_g[(size_t)b * PERM_LDS_CAP + i];

    // ---- chunk 0 (root): A direct from global xb; overlaps the perm copy ----
    float bcol[2];
#pragma unroll
    for (int ct = 0; ct < 2; ++ct) bcol[ct] = bias[wn * 32 + ct * 16 + m16];

    frag_cd acc[4][2];
#pragma unroll
    for (int mt = 0; mt < 4; ++mt)
#pragma unroll
        for (int ct = 0; ct < 2; ++ct) acc[mt][ct] = (frag_cd){0.f, 0.f, 0.f, 0.f};

#pragma unroll
    for (int ks = 0; ks < 4; ++ks) {
        frag_ab af[4];
#pragma unroll
        for (int mt = 0; mt < 4; ++mt)
            af[mt] = *(const frag_ab*)(xb + (B0 + wm * 64 + mt * 16 + m16) * CH + ks * 32 + quad * 8);
#pragma unroll
        for (int ct = 0; ct < 2; ++ct) {
            frag_ab bf = *(const frag_ab*)(Bsw + (size_t)((((ks * 4 + quad) * 8) + wn * 2 + ct) * 16 + m16) * 8);
#pragma unroll
            for (int mt = 0; mt < 4; ++mt)
                acc[mt][ct] = __builtin_amdgcn_mfma_f32_16x16x32_bf16(af[mt], bf, acc[mt][ct], 0, 0, 0);
        }
    }
    __syncthreads();   // perm_lds ready

    // ---- relation loop ----
    const int lrow = tid >> 2;                     // 4-lane group -> one dst row
    const int q4 = tid & 3;
    const uint32_t ch64 = (uint32_t)q4 << 6;       // this lane's 64B channel slice
    const char* xbp = (const char*)xb;
    char* drow = (char*)Ash + lrow * 256;
    const int swz = lrow & 7;

    for (int r = 0; r < N_REL; ++r) {
        const int keyL = lrow * 8 + r;
        const int s = lends[keyL];
        const int e = lends[keyL + 1];
        float a[32];
#pragma unroll
        for (int i = 0; i < 32; ++i) a[i] = 0.f;
        int p0 = perm_lds[(s < e) ? s : 0];
        int p1 = perm_lds[(s + 1 < e) ? s + 1 : ((s < e) ? s : 0)];
        for (int k = s; k < e; k += 2) {
            const char* c0 = xbp + (((size_t)(uint32_t)p0 << 8) | ch64);
            const char* c1 = xbp + (((size_t)(uint32_t)p1 << 8) | ch64);
            const uint4 u0 = *(const uint4*)(c0);
            const uint4 u1 = *(const uint4*)(c0 + 16);
            const uint4 u2 = *(const uint4*)(c0 + 32);
            const uint4 u3 = *(const uint4*)(c0 + 48);
            const uint4 u4 = *(const uint4*)(c1);
            const uint4 u5 = *(const uint4*)(c1 + 16);
            const uint4 u6 = *(const uint4*)(c1 + 32);
            const uint4 u7 = *(const uint4*)(c1 + 48);
            const bool two = (k + 1 < e);
            const int kn = k + 2;
            p0 = perm_lds[(kn < e) ? kn : 0];
            p1 = perm_lds[(kn + 1 < e) ? kn + 1 : 0];
            ACC_U4(u0, 0); ACC_U4(u1, 8); ACC_U4(u2, 16); ACC_U4(u3, 24);
            if (two) { ACC_U4(u4, 0); ACC_U4(u5, 8); ACC_U4(u6, 16); ACC_U4(u7, 24); }
        }
        const int c = e - s;
        const float sc = (c > 1) ? (1.0f / (float)c) : 1.0f;
#pragma unroll
        for (int t = 0; t < 4; ++t) {
            uint4 w;
            w.x = pack2bf(a[t * 8 + 0] * sc, a[t * 8 + 1] * sc);
            w.y = pack2bf(a[t * 8 + 2] * sc, a[t * 8 + 3] * sc);
            w.z = pack2bf(a[t * 8 + 4] * sc, a[t * 8 + 5] * sc);
            w.w = pack2bf(a[t * 8 + 6] * sc, a[t * 8 + 7] * sc);
            *(uint4*)(drow + (((q4 * 4 + t) ^ swz) << 4)) = w;   // swizzled A-tile write
        }
        __syncthreads();
        // ---- MFMA chunk r+1: A from LDS (swizzled ds_read_b128), B from L2-hot Bsw ----
        const short* Bc = Bsw + (size_t)(r + 1) * 2048 * 8;
#pragma unroll
        for (int ks = 0; ks < 4; ++ks) {
            frag_ab af[4];
#pragma unroll
            for (int mt = 0; mt < 4; ++mt) {
                const int lr = wm * 64 + mt * 16 + m16;
                af[mt] = *(const frag_ab*)((const char*)Ash + lr * 256 + (((ks * 4 + quad) ^ (lr & 7)) << 4));
            }
#pragma unroll
            for (int ct = 0; ct < 2; ++ct) {
                frag_ab bf = *(const frag_ab*)(Bc + (size_t)((((ks * 4 + quad) * 8) + wn * 2 + ct) * 16 + m16) * 8);
#pragma unroll
                for (int mt = 0; mt < 4; ++mt)
                    acc[mt][ct] = __builtin_amdgcn_mfma_f32_16x16x32_bf16(af[mt], bf, acc[mt][ct], 0, 0, 0);
            }
        }
        __syncthreads();
    }

    // ---- epilogue ----
#pragma unroll
    for (int mt = 0; mt < 4; ++mt) {
#pragma unroll
        for (int ct = 0; ct < 2; ++ct) {
            const long row0 = B0 + wm * 64 + mt * 16 + quad * 4;
            const int col = wn * 32 + ct * 16 + m16;
#pragma unroll
            for (int rg = 0; rg < 4; ++rg) {
                const long rr = row0 + rg;
                if (rr < N_NODES) out[rr * CH + col] = acc[mt][ct][rg] + bcol[ct];
            }
        }
    }
}

// ======================= fallback tiers (round-1 code) =======================

__global__ void count_rd_kernel(const int* __restrict__ ei, const int* __restrict__ et,
                                int* __restrict__ cnt) {
    int e = blockIdx.x * 256 + threadIdx.x;
    if (e < N_EDGES) {
        int dst = ei[N_EDGES + e];
        int r = et[e];
        atomicAdd(&cnt[r * N_NODES + dst], 1);
    }
}

__global__ void scatter_kernel(const int* __restrict__ ei, const int* __restrict__ et,
                               const float* __restrict__ x, float* __restrict__ sums,
                               int rel) {
    int gid = (blockIdx.x * 256 + threadIdx.x) >> 5;
    int lane = threadIdx.x & 31;
    int ngroups = gridDim.x * 8;
    for (int e = gid; e < N_EDGES; e += ngroups) {
        if (et[e] != rel) continue;
        int src = ei[e];
        int dst = ei[N_EDGES + e];
        float4 v = ((const float4*)(x + (size_t)src * CH))[lane];
        float* s = sums + (size_t)dst * CH + (size_t)lane * 4;
        atomicAdd(s + 0, v.x);
        atomicAdd(s + 1, v.y);
        atomicAdd(s + 2, v.z);
        atomicAdd(s + 3, v.w);
    }
}

__global__ __launch_bounds__(256, 2)
void gemm_kernel(const float* __restrict__ A, const float* __restrict__ B,
                 const float* __restrict__ bias, const int* __restrict__ cnt,
                 float* __restrict__ out, int accumulate) {
    const int wave = threadIdx.x >> 6;
    const int lane = threadIdx.x & 63;
    const int m16 = lane & 15;
    const int quad = lane >> 4;

    frag_ab bfrag[4][8];
#pragma unroll
    for (int ks = 0; ks < 4; ++ks) {
        const int kb = ks * 32 + quad * 8;
#pragma unroll
        for (int ct = 0; ct < 8; ++ct) {
            const int col = ct * 16 + m16;
            frag_ab f;
#pragma unroll
            for (int j = 0; j < 8; ++j)
                f[j] = f2bs(B[(size_t)(kb + j) * CH + col]);
            bfrag[ks][ct] = f;
        }
    }

    const int nstrips = (N_NODES + 63) / 64;
    for (int strip = blockIdx.x; strip < nstrips; strip += gridDim.x) {
        const int row = strip * 64 + wave * 16 + m16;
        const bool valid = row < N_NODES;
        float scale = 1.0f;
        if (cnt != nullptr && valid) {
            int c = cnt[row];
            if (c > 1) scale = 1.0f / (float)c;
        }
        const float4* arow = (const float4*)(A + (size_t)(valid ? row : 0) * CH);
        frag_cd acc[8];
#pragma unroll
        for (int ct = 0; ct < 8; ++ct) acc[ct] = (frag_cd){0.f, 0.f, 0.f, 0.f};
#pragma unroll
        for (int ks = 0; ks < 4; ++ks) {
            float4 a0 = arow[ks * 8 + quad * 2];
            float4 a1 = arow[ks * 8 + quad * 2 + 1];
            frag_ab af;
            af[0] = f2bs(a0.x * scale); af[1] = f2bs(a0.y * scale);
            af[2] = f2bs(a0.z * scale); af[3] = f2bs(a0.w * scale);
            af[4] = f2bs(a1.x * scale); af[5] = f2bs(a1.y * scale);
            af[6] = f2bs(a1.z * scale); af[7] = f2bs(a1.w * scale);
#pragma unroll
            for (int ct = 0; ct < 8; ++ct)
                acc[ct] = __builtin_amdgcn_mfma_f32_16x16x32_bf16(af, bfrag[ks][ct], acc[ct], 0, 0, 0);
        }
        const int obase = strip * 64 + wave * 16 + quad * 4;
#pragma unroll
        for (int ct = 0; ct < 8; ++ct) {
            const int col = ct * 16 + m16;
#pragma unroll
            for (int rg = 0; rg < 4; ++rg) {
                const int r = obase + rg;
                if (r < N_NODES) {
                    const size_t idx = (size_t)r * CH + col;
                    if (accumulate) out[idx] += acc[ct][rg];
                    else out[idx] = acc[ct][rg] + bias[col];
                }
            }
        }
    }
}

__global__ void edge_transform_kernel(const int* __restrict__ ei, const int* __restrict__ et,
                                      const float* __restrict__ x, const float* __restrict__ W,
                                      const int* __restrict__ cnt, float* __restrict__ out) {
    __shared__ float xs[CH];
    const int tid = threadIdx.x;
    for (int e = blockIdx.x; e < N_EDGES; e += gridDim.x) {
        const int src = ei[e];
        const int dst = ei[N_EDGES + e];
        const int r = et[e];
        __syncthreads();
        xs[tid] = x[(size_t)src * CH + tid];
        __syncthreads();
        const int c = cnt[r * N_NODES + dst];
        const float scale = (c > 1) ? (1.0f / (float)c) : 1.0f;
        const float* Wr = W + (size_t)r * CH * CH;
        float acc = 0.f;
#pragma unroll 8
        for (int k = 0; k < CH; ++k) acc += xs[k] * Wr[(size_t)k * CH + tid];
        atomicAdd(&out[(size_t)dst * CH + tid], acc * scale);
    }
}

// ======================= launch =======================

static inline size_t al512(size_t x) { return (x + 511) & ~(size_t)511; }

extern "C" void kernel_launch(void* const* d_in, const int* in_sizes, int n_in,
                              void* d_out, int out_size, void* d_ws, size_t ws_size,
                              hipStream_t stream) {
    const float* x    = (const float*)d_in[0];
    const int*   ei   = (const int*)d_in[1];   // [2, E]: row0=src, row1=dst
    const int*   et   = (const int*)d_in[2];   // [E]
    const float* W    = (const float*)d_in[3]; // [R,128,128]
    const float* root = (const float*)d_in[4]; // [128,128]
    const float* bias = (const float*)d_in[5]; // [128]
    float* out = (float*)d_out;

    // ---- tier-1 workspace layout ----
    size_t o = 0;
    const size_t o_ents = o; o += al512((size_t)NCHUNK * NSLOT * 4);          // 48.9 MB
    const size_t o_lens = o; o += al512((size_t)NCHUNK * NBKT * 4);           // 2.45 MB
    const size_t o_perm = o; o += al512((size_t)NBKT * PERM_LDS_CAP * 4);     // 12.8 MB
    const size_t o_ends = o; o += al512((size_t)NBKT * 1024 * 4);             // 3.2 MB
    const size_t o_bsw  = o; o += al512((size_t)9 * 2048 * 16);
    const size_t o_xb   = o; o += al512((size_t)N_PAD * CH * 2);              // 25.6 MB
    const size_t need_t1 = o;

    const size_t cnt_bytes = (size_t)N_REL * N_NODES * sizeof(int);
    const size_t cnt_rsv   = al512(cnt_bytes);
    const size_t sums51    = (size_t)N_NODES * CH * sizeof(float);

    char* ws = (char*)d_ws;
    if (ws_size >= need_t1) {
        uint32_t* ents   = (uint32_t*)(ws + o_ents);
        int*      lens   = (int*)(ws + o_lens);
        int*      perm_g = (int*)(ws + o_perm);
        int*      ends_g = (int*)(ws + o_ends);
        short*    Bsw    = (short*)(ws + o_bsw);
        short*    xb     = (short*)(ws + o_xb);

        prep_kernel<<<NCHUNK, 256, 0, stream>>>(ei, et, ents, lens, root, W, Bsw);
        bin_kernel<<<NBKT, 512, 0, stream>>>(ents, lens, perm_g, ends_g, x, xb);
        rgcn_fused<<<NBKT, 512, 0, stream>>>(ends_g, perm_g, xb, Bsw, bias, out);
    } else if (ws_size >= cnt_rsv + sums51) {
        int*   cnt  = (int*)d_ws;
        float* sums = (float*)((char*)d_ws + cnt_rsv);
        hipMemsetAsync(cnt, 0, cnt_bytes, stream);
        count_rd_kernel<<<(N_EDGES + 255) / 256, 256, 0, stream>>>(ei, et, cnt);
        gemm_kernel<<<512, 256, 0, stream>>>(x, root, bias, nullptr, out, 0);
        for (int r = 0; r < N_REL; ++r) {
            hipMemsetAsync(sums, 0, sums51, stream);
            scatter_kernel<<<6400, 256, 0, stream>>>(ei, et, x, sums, r);
            gemm_kernel<<<512, 256, 0, stream>>>(sums, W + (size_t)r * CH * CH,
                                                 nullptr, cnt + (size_t)r * N_NODES, out, 1);
        }
    } else {
        int* cnt = (int*)d_ws;
        hipMemsetAsync(cnt, 0, cnt_bytes, stream);
        count_rd_kernel<<<(N_EDGES + 255) / 256, 256, 0, stream>>>(ei, et, cnt);
        gemm_kernel<<<512, 256, 0, stream>>>(x, root, bias, nullptr, out, 0);
        edge_transform_kernel<<<65536, CH, 0, stream>>>(ei, et, x, W, cnt, out);
    }
}

// Round 10
// 270.096 us; speedup vs baseline: 1.1076x; 1.1076x over previous
//
#include <hip/hip_runtime.h>
#include <hip/hip_bf16.h>
#include <stdint.h>

#define N_NODES 100000
#define N_EDGES 1600000
#define CH 128
#define N_REL 8
#define N_PAD 100096            // N_NODES rounded up to multiple of 128
#define N_KEYS (N_NODES * N_REL)

#define NBKT 782                // N_PAD / 128 buckets (= bin/fused grid)
#define NCHUNK 782              // edge chunks (one per prep block)
#define CHUNK_E 2048            // edges per chunk (256 thr x 8)
#define OFFS_STRIDE 784         // per-chunk offset row (782 buckets + total + pad)
#define PERM_LDS_CAP 4096       // per-bucket edges ~2046 +- 45 -> 45-sigma margin

using frag_ab = __attribute__((ext_vector_type(8))) short;  // 8 bf16
using frag_cd = __attribute__((ext_vector_type(4))) float;  // 4 fp32

__device__ __forceinline__ short f2bs(float f) {
    union { __hip_bfloat16 h; short s; } u;
    u.h = __float2bfloat16(f);
    return u.s;
}

__device__ __forceinline__ uint32_t pack2bf(float a, float b) {
    union { __hip_bfloat16 h; unsigned short s; } ua, ub;
    ua.h = __float2bfloat16(a); ub.h = __float2bfloat16(b);
    return (uint32_t)ua.s | ((uint32_t)ub.s << 16);
}

__device__ __forceinline__ float bf_lo(uint32_t u) { return __uint_as_float(u << 16); }
__device__ __forceinline__ float bf_hi(uint32_t u) { return __uint_as_float(u & 0xffff0000u); }

// ======================= prep: compact per-chunk CSR =======================
// R10: R8/R9 prologues moved ~200MB of which only ~110MB was useful (48.9MB
// slot array, 87% garbage, written AND refetched). Now: pass 1 packs entries
// to LDS + counts per bucket; 1024-wide LDS scan -> exclusive offsets
// (offs[c][784] to global); pass 2 places entries at exact compact positions
// in LDS; linear 8KB uint4 writeout. Entry: src<<10 | (dst&127)<<3 | rel.
// Write traffic 48.9 -> 8.9 MB. Zero global atomics. bconv rides on blocks 0-71.

__global__ __launch_bounds__(256)
void prep_kernel(const int* __restrict__ ei, const int* __restrict__ et,
                 uint32_t* __restrict__ ents, int* __restrict__ offs,
                 const float* __restrict__ root, const float* __restrict__ W,
                 short* __restrict__ Bsw) {
    __shared__ uint32_t esave[CHUNK_E];   // 8 KB: packed entries, arrival order
    __shared__ uint32_t csave[CHUNK_E];   // 8 KB: compact (bucket-sorted) entries
    __shared__ short bsave[CHUNK_E];      // 4 KB: bucket id per entry (-1 invalid)
    __shared__ int cnt[NBKT];             // count -> cursor
    __shared__ int scan_t[256];
    const int tid = threadIdx.x;
    const int c = blockIdx.x;
    const int g = blockIdx.x * 256 + tid;

    // --- bconv rides on blocks 0..71 ---
    if (g < 9 * 2048) {
        int chunk = g >> 11, entry = g & 2047;
        int m16 = entry & 15, ct = (entry >> 4) & 7, quad = (entry >> 7) & 3, ks = entry >> 9;
        const float* src = (chunk == 0) ? root : W + (size_t)(chunk - 1) * CH * CH;
        int col = ct * 16 + m16, kb = ks * 32 + quad * 8;
        frag_ab f;
#pragma unroll
        for (int j = 0; j < 8; ++j) f[j] = f2bs(src[(size_t)(kb + j) * CH + col]);
        *(frag_ab*)(Bsw + (size_t)g * 8) = f;
    }

    for (int i = tid; i < NBKT; i += 256) cnt[i] = 0;
    __syncthreads();
    // --- pass 1: read edges (coalesced), pack to LDS, count per bucket ---
#pragma unroll
    for (int j = 0; j < 8; ++j) {
        const int li = j * 256 + tid;
        const int e = c * CHUNK_E + li;
        if (e < N_EDGES) {
            const int dst = ei[N_EDGES + e];
            const int src = ei[e];
            const int r = et[e];
            const int b = dst >> 7;
            atomicAdd(&cnt[b], 1);
            esave[li] = ((uint32_t)src << 10) | ((uint32_t)(dst & 127) << 3) | (uint32_t)r;
            bsave[li] = (short)b;
        } else {
            bsave[li] = -1;
        }
    }
    __syncthreads();
    // --- scan cnt[0..781] -> exclusive offsets (thread t owns 4t..4t+3) ---
    const int b4 = 4 * tid;
    int c0 = (b4 < NBKT) ? cnt[b4] : 0;
    int c1 = (b4 + 1 < NBKT) ? cnt[b4 + 1] : 0;
    int c2 = (b4 + 2 < NBKT) ? cnt[b4 + 2] : 0;
    int c3 = (b4 + 3 < NBKT) ? cnt[b4 + 3] : 0;
    const int s4 = c0 + c1 + c2 + c3;
    scan_t[tid] = s4;
    __syncthreads();
    for (int st = 1; st < 256; st <<= 1) {    // Hillis-Steele inclusive
        int u = (tid >= st) ? scan_t[tid - st] : 0;
        __syncthreads();
        scan_t[tid] += u;
        __syncthreads();
    }
    const int excl = scan_t[tid] - s4;
    const int total = scan_t[255];
    {
        const int o0 = excl, o1 = o0 + c0, o2 = o1 + c1, o3 = o2 + c2;
        int* og = offs + (size_t)c * OFFS_STRIDE;
        if (b4 < NBKT)     { cnt[b4]     = o0; og[b4]     = o0; }
        if (b4 + 1 < NBKT) { cnt[b4 + 1] = o1; og[b4 + 1] = o1; }
        if (b4 + 2 < NBKT) { cnt[b4 + 2] = o2; og[b4 + 2] = o2; }
        if (b4 + 3 < NBKT) { cnt[b4 + 3] = o3; og[b4 + 3] = o3; }
        if (tid == 0) og[NBKT] = total;
    }
    __syncthreads();
    // --- pass 2: place entries at compact positions ---
#pragma unroll
    for (int j = 0; j < 8; ++j) {
        const int li = j * 256 + tid;
        const int b = bsave[li];
        if (b >= 0) {
            const int pos = atomicAdd(&cnt[b], 1);
            csave[pos] = esave[li];
        }
    }
    __syncthreads();
    // --- linear writeout: 8 KB as uint4 (2 iters/thread) ---
    {
        const uint4* cs = (const uint4*)csave;
        uint4* dg = (uint4*)(ents + (size_t)c * CHUNK_E);
#pragma unroll
        for (int i = 0; i < 2; ++i) dg[tid + 256 * i] = cs[tid + 256 * i];
    }
}

// ======================= bin: slice-copy + key sort (+xconv ride-along) =======================
// Block b: read offs[c][b]/[b+1] per chunk (lines shared by 16 sibling b's ->
// L2-warm), pair-scan slice lengths -> stage bases, copy each chunk's dense
// slice into stage[] (valid-only reads, no ballot/filter), then hist/scan/
// scatter -> global perm + local ends. xconv (77MB streaming) rides up front.

__global__ __launch_bounds__(512)
void bin_kernel(const uint32_t* __restrict__ ents, const int* __restrict__ offs,
                int* __restrict__ perm_g, int* __restrict__ ends_g,
                const float* __restrict__ x, short* __restrict__ xb) {
    __shared__ uint32_t stage[PERM_LDS_CAP];   // 16 KB compact entries
    __shared__ int soff[NCHUNK];               // slice start per chunk
    __shared__ int slen[NCHUNK];               // slice len per chunk
    __shared__ int sbase[NCHUNK];              // stage base per chunk
    __shared__ int hist[1024];
    __shared__ int cursor[1024];
    __shared__ int shl[512];
    const int tid = threadIdx.x;
    const int b = blockIdx.x;

    // --- xconv grid-stride (4 iterations/thread across the 782x512 grid) ---
    {
        const int nst = NBKT * 512;
        const float4* xp = (const float4*)x;
        for (int gi = b * 512 + tid; gi < N_NODES * CH / 8; gi += nst) {
            float4 a = xp[(size_t)gi * 2], bb = xp[(size_t)gi * 2 + 1];
            frag_ab f;
            f[0] = f2bs(a.x); f[1] = f2bs(a.y); f[2] = f2bs(a.z); f[3] = f2bs(a.w);
            f[4] = f2bs(bb.x); f[5] = f2bs(bb.y); f[6] = f2bs(bb.z); f[7] = f2bs(bb.w);
            *(frag_ab*)(xb + (size_t)gi * 8) = f;
        }
    }

    // --- slice bounds ---
    for (int c = tid; c < NCHUNK; c += 512) {
        const int s = offs[(size_t)c * OFFS_STRIDE + b];
        const int e = offs[(size_t)c * OFFS_STRIDE + b + 1];
        soff[c] = s;
        slen[c] = e - s;
    }
    hist[tid] = 0; hist[tid + 512] = 0;
    __syncthreads();
    // --- pair-scan slice lengths -> per-chunk stage base ---
    {
        const int t2 = 2 * tid;
        const int h0 = (t2 < NCHUNK) ? slen[t2] : 0;
        const int h1 = (t2 + 1 < NCHUNK) ? slen[t2 + 1] : 0;
        const int s2 = h0 + h1;
        shl[tid] = s2;
        __syncthreads();
        for (int st = 1; st < 512; st <<= 1) {
            int u = (tid >= st) ? shl[tid - st] : 0;
            __syncthreads();
            shl[tid] += u;
            __syncthreads();
        }
        const int excl = shl[tid] - s2;
        if (t2 < NCHUNK)     sbase[t2]     = excl;
        if (t2 + 1 < NCHUNK) sbase[t2 + 1] = excl + h0;
    }
    __syncthreads();
    // --- copy slices into stage (thread t owns chunks 2t, 2t+1) ---
#pragma unroll
    for (int k = 0; k < 2; ++k) {
        const int c = 2 * tid + k;
        if (c < NCHUNK) {
            const int s = soff[c], n_c = slen[c], base = sbase[c];
            const uint32_t* src = ents + (size_t)c * CHUNK_E + s;
            for (int i = 0; i < n_c; ++i) {
                const int pos = base + i;
                if (pos < PERM_LDS_CAP) stage[pos] = src[i];
            }
        }
    }
    __syncthreads();
    int n = shl[511];                       // total entries this bucket
    if (n > PERM_LDS_CAP) n = PERM_LDS_CAP;
    // --- hist / scan / scatter by key = (dst&127)*8 + rel ---
    for (int i = tid; i < n; i += 512) atomicAdd(&hist[stage[i] & 1023], 1);
    __syncthreads();
    const int h0 = hist[2 * tid], h1 = hist[2 * tid + 1];
    const int s2 = h0 + h1;
    shl[tid] = s2;
    __syncthreads();
    for (int st = 1; st < 512; st <<= 1) {
        int u = (tid >= st) ? shl[tid - st] : 0;
        __syncthreads();
        shl[tid] += u;
        __syncthreads();
    }
    const int excl = shl[tid] - s2;
    cursor[2 * tid]     = excl;
    cursor[2 * tid + 1] = excl + h0;
    {   // local (0-based) segment ends, clamped so fused LDS reads are in-bounds
        int e1 = excl + h0, e2 = excl + h0 + h1;
        ends_g[(size_t)b * 1024 + 2 * tid]     = (e1 > PERM_LDS_CAP) ? PERM_LDS_CAP : e1;
        ends_g[(size_t)b * 1024 + 2 * tid + 1] = (e2 > PERM_LDS_CAP) ? PERM_LDS_CAP : e2;
    }
    __syncthreads();
    for (int i = tid; i < n; i += 512) {
        const uint32_t v = stage[i];
        const int pos = atomicAdd(&cursor[v & 1023], 1);
        if (pos < PERM_LDS_CAP) perm_g[(size_t)b * PERM_LDS_CAP + pos] = (int)(v >> 10);
    }
}

// ======================= FUSED aggregate + GEMM (unchanged, 131us @ R8) =======================
#define ACC_U4(U, B)                                            \
    do {                                                        \
        a[(B)+0] += bf_lo((U).x); a[(B)+1] += bf_hi((U).x);     \
        a[(B)+2] += bf_lo((U).y); a[(B)+3] += bf_hi((U).y);     \
        a[(B)+4] += bf_lo((U).z); a[(B)+5] += bf_hi((U).z);     \
        a[(B)+6] += bf_lo((U).w); a[(B)+7] += bf_hi((U).w);     \
    } while (0)

__global__ __launch_bounds__(512, 4)
void rgcn_fused(const int* __restrict__ ends_g, const int* __restrict__ perm_g,
                const short* __restrict__ xb, const short* __restrict__ Bsw,
                const float* __restrict__ bias, float* __restrict__ out) {
    __shared__ short Ash[128 * 128];        // 32 KB swizzled A-tile
    __shared__ int perm_lds[PERM_LDS_CAP];  // 16 KB
    __shared__ int lends[1025];             // local ends; lends[0] = 0
    const int tid = threadIdx.x;
    const int wave = tid >> 6, lane = tid & 63;
    const int m16 = lane & 15, quad = lane >> 4;
    const int wm = wave >> 2, wn = wave & 3;     // wave tile: 64 rows x 32 cols
    const int b = blockIdx.x;
    const long B0 = (long)b * 128;

    if (tid == 0) { lends[0] = 0; perm_lds[0] = 0; }
    for (int i = tid; i < 1024; i += 512) lends[1 + i] = ends_g[(size_t)b * 1024 + i];
    __syncthreads();
    const int nperm = lends[1024];
    for (int i = tid; i < nperm; i += 512) perm_lds[i] = perm_g[(size_t)b * PERM_LDS_CAP + i];

    // ---- chunk 0 (root): A direct from global xb; overlaps the perm copy ----
    float bcol[2];
#pragma unroll
    for (int ct = 0; ct < 2; ++ct) bcol[ct] = bias[wn * 32 + ct * 16 + m16];

    frag_cd acc[4][2];
#pragma unroll
    for (int mt = 0; mt < 4; ++mt)
#pragma unroll
        for (int ct = 0; ct < 2; ++ct) acc[mt][ct] = (frag_cd){0.f, 0.f, 0.f, 0.f};

#pragma unroll
    for (int ks = 0; ks < 4; ++ks) {
        frag_ab af[4];
#pragma unroll
        for (int mt = 0; mt < 4; ++mt)
            af[mt] = *(const frag_ab*)(xb + (B0 + wm * 64 + mt * 16 + m16) * CH + ks * 32 + quad * 8);
#pragma unroll
        for (int ct = 0; ct < 2; ++ct) {
            frag_ab bf = *(const frag_ab*)(Bsw + (size_t)((((ks * 4 + quad) * 8) + wn * 2 + ct) * 16 + m16) * 8);
#pragma unroll
            for (int mt = 0; mt < 4; ++mt)
                acc[mt][ct] = __builtin_amdgcn_mfma_f32_16x16x32_bf16(af[mt], bf, acc[mt][ct], 0, 0, 0);
        }
    }
    __syncthreads();   // perm_lds ready

    // ---- relation loop ----
    const int lrow = tid >> 2;                     // 4-lane group -> one dst row
    const int q4 = tid & 3;
    const uint32_t ch64 = (uint32_t)q4 << 6;       // this lane's 64B channel slice
    const char* xbp = (const char*)xb;
    char* drow = (char*)Ash + lrow * 256;
    const int swz = lrow & 7;

    for (int r = 0; r < N_REL; ++r) {
        const int keyL = lrow * 8 + r;
        const int s = lends[keyL];
        const int e = lends[keyL + 1];
        float a[32];
#pragma unroll
        for (int i = 0; i < 32; ++i) a[i] = 0.f;
        int p0 = perm_lds[(s < e) ? s : 0];
        int p1 = perm_lds[(s + 1 < e) ? s + 1 : ((s < e) ? s : 0)];
        for (int k = s; k < e; k += 2) {
            const char* c0 = xbp + (((size_t)(uint32_t)p0 << 8) | ch64);
            const char* c1 = xbp + (((size_t)(uint32_t)p1 << 8) | ch64);
            const uint4 u0 = *(const uint4*)(c0);
            const uint4 u1 = *(const uint4*)(c0 + 16);
            const uint4 u2 = *(const uint4*)(c0 + 32);
            const uint4 u3 = *(const uint4*)(c0 + 48);
            const uint4 u4 = *(const uint4*)(c1);
            const uint4 u5 = *(const uint4*)(c1 + 16);
            const uint4 u6 = *(const uint4*)(c1 + 32);
            const uint4 u7 = *(const uint4*)(c1 + 48);
            const bool two = (k + 1 < e);
            const int kn = k + 2;
            p0 = perm_lds[(kn < e) ? kn : 0];
            p1 = perm_lds[(kn + 1 < e) ? kn + 1 : 0];
            ACC_U4(u0, 0); ACC_U4(u1, 8); ACC_U4(u2, 16); ACC_U4(u3, 24);
            if (two) { ACC_U4(u4, 0); ACC_U4(u5, 8); ACC_U4(u6, 16); ACC_U4(u7, 24); }
        }
        const int c = e - s;
        const float sc = (c > 1) ? (1.0f / (float)c) : 1.0f;
#pragma unroll
        for (int t = 0; t < 4; ++t) {
            uint4 w;
            w.x = pack2bf(a[t * 8 + 0] * sc, a[t * 8 + 1] * sc);
            w.y = pack2bf(a[t * 8 + 2] * sc, a[t * 8 + 3] * sc);
            w.z = pack2bf(a[t * 8 + 4] * sc, a[t * 8 + 5] * sc);
            w.w = pack2bf(a[t * 8 + 6] * sc, a[t * 8 + 7] * sc);
            *(uint4*)(drow + (((q4 * 4 + t) ^ swz) << 4)) = w;   // swizzled A-tile write
        }
        __syncthreads();
        // ---- MFMA chunk r+1: A from LDS (swizzled ds_read_b128), B from L2-hot Bsw ----
        const short* Bc = Bsw + (size_t)(r + 1) * 2048 * 8;
#pragma unroll
        for (int ks = 0; ks < 4; ++ks) {
            frag_ab af[4];
#pragma unroll
            for (int mt = 0; mt < 4; ++mt) {
                const int lr = wm * 64 + mt * 16 + m16;
                af[mt] = *(const frag_ab*)((const char*)Ash + lr * 256 + (((ks * 4 + quad) ^ (lr & 7)) << 4));
            }
#pragma unroll
            for (int ct = 0; ct < 2; ++ct) {
                frag_ab bf = *(const frag_ab*)(Bc + (size_t)((((ks * 4 + quad) * 8) + wn * 2 + ct) * 16 + m16) * 8);
#pragma unroll
                for (int mt = 0; mt < 4; ++mt)
                    acc[mt][ct] = __builtin_amdgcn_mfma_f32_16x16x32_bf16(af[mt], bf, acc[mt][ct], 0, 0, 0);
            }
        }
        __syncthreads();
    }

    // ---- epilogue ----
#pragma unroll
    for (int mt = 0; mt < 4; ++mt) {
#pragma unroll
        for (int ct = 0; ct < 2; ++ct) {
            const long row0 = B0 + wm * 64 + mt * 16 + quad * 4;
            const int col = wn * 32 + ct * 16 + m16;
#pragma unroll
            for (int rg = 0; rg < 4; ++rg) {
                const long rr = row0 + rg;
                if (rr < N_NODES) out[rr * CH + col] = acc[mt][ct][rg] + bcol[ct];
            }
        }
    }
}

// ======================= fallback tiers (round-1 code) =======================

__global__ void count_rd_kernel(const int* __restrict__ ei, const int* __restrict__ et,
                                int* __restrict__ cnt) {
    int e = blockIdx.x * 256 + threadIdx.x;
    if (e < N_EDGES) {
        int dst = ei[N_EDGES + e];
        int r = et[e];
        atomicAdd(&cnt[r * N_NODES + dst], 1);
    }
}

__global__ void scatter_kernel(const int* __restrict__ ei, const int* __restrict__ et,
                               const float* __restrict__ x, float* __restrict__ sums,
                               int rel) {
    int gid = (blockIdx.x * 256 + threadIdx.x) >> 5;
    int lane = threadIdx.x & 31;
    int ngroups = gridDim.x * 8;
    for (int e = gid; e < N_EDGES; e += ngroups) {
        if (et[e] != rel) continue;
        int src = ei[e];
        int dst = ei[N_EDGES + e];
        float4 v = ((const float4*)(x + (size_t)src * CH))[lane];
        float* s = sums + (size_t)dst * CH + (size_t)lane * 4;
        atomicAdd(s + 0, v.x);
        atomicAdd(s + 1, v.y);
        atomicAdd(s + 2, v.z);
        atomicAdd(s + 3, v.w);
    }
}

__global__ __launch_bounds__(256, 2)
void gemm_kernel(const float* __restrict__ A, const float* __restrict__ B,
                 const float* __restrict__ bias, const int* __restrict__ cnt,
                 float* __restrict__ out, int accumulate) {
    const int wave = threadIdx.x >> 6;
    const int lane = threadIdx.x & 63;
    const int m16 = lane & 15;
    const int quad = lane >> 4;

    frag_ab bfrag[4][8];
#pragma unroll
    for (int ks = 0; ks < 4; ++ks) {
        const int kb = ks * 32 + quad * 8;
#pragma unroll
        for (int ct = 0; ct < 8; ++ct) {
            const int col = ct * 16 + m16;
            frag_ab f;
#pragma unroll
            for (int j = 0; j < 8; ++j)
                f[j] = f2bs(B[(size_t)(kb + j) * CH + col]);
            bfrag[ks][ct] = f;
        }
    }

    const int nstrips = (N_NODES + 63) / 64;
    for (int strip = blockIdx.x; strip < nstrips; strip += gridDim.x) {
        const int row = strip * 64 + wave * 16 + m16;
        const bool valid = row < N_NODES;
        float scale = 1.0f;
        if (cnt != nullptr && valid) {
            int c = cnt[row];
            if (c > 1) scale = 1.0f / (float)c;
        }
        const float4* arow = (const float4*)(A + (size_t)(valid ? row : 0) * CH);
        frag_cd acc[8];
#pragma unroll
        for (int ct = 0; ct < 8; ++ct) acc[ct] = (frag_cd){0.f, 0.f, 0.f, 0.f};
#pragma unroll
        for (int ks = 0; ks < 4; ++ks) {
            float4 a0 = arow[ks * 8 + quad * 2];
            float4 a1 = arow[ks * 8 + quad * 2 + 1];
            frag_ab af;
            af[0] = f2bs(a0.x * scale); af[1] = f2bs(a0.y * scale);
            af[2] = f2bs(a0.z * scale); af[3] = f2bs(a0.w * scale);
            af[4] = f2bs(a1.x * scale); af[5] = f2bs(a1.y * scale);
            af[6] = f2bs(a1.z * scale); af[7] = f2bs(a1.w * scale);
#pragma unroll
            for (int ct = 0; ct < 8; ++ct)
                acc[ct] = __builtin_amdgcn_mfma_f32_16x16x32_bf16(af, bfrag[ks][ct], acc[ct], 0, 0, 0);
        }
        const int obase = strip * 64 + wave * 16 + quad * 4;
#pragma unroll
        for (int ct = 0; ct < 8; ++ct) {
            const int col = ct * 16 + m16;
#pragma unroll
            for (int rg = 0; rg < 4; ++rg) {
                const int r = obase + rg;
                if (r < N_NODES) {
                    const size_t idx = (size_t)r * CH + col;
                    if (accumulate) out[idx] += acc[ct][rg];
                    else out[idx] = acc[ct][rg] + bias[col];
                }
            }
        }
    }
}

__global__ void edge_transform_kernel(const int* __restrict__ ei, const int* __restrict__ et,
                                      const float* __restrict__ x, const float* __restrict__ W,
                                      const int* __restrict__ cnt, float* __restrict__ out) {
    __shared__ float xs[CH];
    const int tid = threadIdx.x;
    for (int e = blockIdx.x; e < N_EDGES; e += gridDim.x) {
        const int src = ei[e];
        const int dst = ei[N_EDGES + e];
        const int r = et[e];
        __syncthreads();
        xs[tid] = x[(size_t)src * CH + tid];
        __syncthreads();
        const int c = cnt[r * N_NODES + dst];
        const float scale = (c > 1) ? (1.0f / (float)c) : 1.0f;
        const float* Wr = W + (size_t)r * CH * CH;
        float acc = 0.f;
#pragma unroll 8
        for (int k = 0; k < CH; ++k) acc += xs[k] * Wr[(size_t)k * CH + tid];
        atomicAdd(&out[(size_t)dst * CH + tid], acc * scale);
    }
}

// ======================= launch =======================

static inline size_t al512(size_t x) { return (x + 511) & ~(size_t)511; }

extern "C" void kernel_launch(void* const* d_in, const int* in_sizes, int n_in,
                              void* d_out, int out_size, void* d_ws, size_t ws_size,
                              hipStream_t stream) {
    const float* x    = (const float*)d_in[0];
    const int*   ei   = (const int*)d_in[1];   // [2, E]: row0=src, row1=dst
    const int*   et   = (const int*)d_in[2];   // [E]
    const float* W    = (const float*)d_in[3]; // [R,128,128]
    const float* root = (const float*)d_in[4]; // [128,128]
    const float* bias = (const float*)d_in[5]; // [128]
    float* out = (float*)d_out;

    // ---- tier-1 workspace layout (compact per-chunk CSR) ----
    size_t o = 0;
    const size_t o_ents = o; o += al512((size_t)NCHUNK * CHUNK_E * 4);        // 6.4 MB
    const size_t o_offs = o; o += al512((size_t)NCHUNK * OFFS_STRIDE * 4);    // 2.45 MB
    const size_t o_perm = o; o += al512((size_t)NBKT * PERM_LDS_CAP * 4);     // 12.8 MB
    const size_t o_ends = o; o += al512((size_t)NBKT * 1024 * 4);             // 3.2 MB
    const size_t o_bsw  = o; o += al512((size_t)9 * 2048 * 16);
    const size_t o_xb   = o; o += al512((size_t)N_PAD * CH * 2);              // 25.6 MB
    const size_t need_t1 = o;

    const size_t cnt_bytes = (size_t)N_REL * N_NODES * sizeof(int);
    const size_t cnt_rsv   = al512(cnt_bytes);
    const size_t sums51    = (size_t)N_NODES * CH * sizeof(float);

    char* ws = (char*)d_ws;
    if (ws_size >= need_t1) {
        uint32_t* ents   = (uint32_t*)(ws + o_ents);
        int*      offs   = (int*)(ws + o_offs);
        int*      perm_g = (int*)(ws + o_perm);
        int*      ends_g = (int*)(ws + o_ends);
        short*    Bsw    = (short*)(ws + o_bsw);
        short*    xb     = (short*)(ws + o_xb);

        prep_kernel<<<NCHUNK, 256, 0, stream>>>(ei, et, ents, offs, root, W, Bsw);
        bin_kernel<<<NBKT, 512, 0, stream>>>(ents, offs, perm_g, ends_g, x, xb);
        rgcn_fused<<<NBKT, 512, 0, stream>>>(ends_g, perm_g, xb, Bsw, bias, out);
    } else if (ws_size >= cnt_rsv + sums51) {
        int*   cnt  = (int*)d_ws;
        float* sums = (float*)((char*)d_ws + cnt_rsv);
        hipMemsetAsync(cnt, 0, cnt_bytes, stream);
        count_rd_kernel<<<(N_EDGES + 255) / 256, 256, 0, stream>>>(ei, et, cnt);
        gemm_kernel<<<512, 256, 0, stream>>>(x, root, bias, nullptr, out, 0);
        for (int r = 0; r < N_REL; ++r) {
            hipMemsetAsync(sums, 0, sums51, stream);
            scatter_kernel<<<6400, 256, 0, stream>>>(ei, et, x, sums, r);
            gemm_kernel<<<512, 256, 0, stream>>>(sums, W + (size_t)r * CH * CH,
                                                 nullptr, cnt + (size_t)r * N_NODES, out, 1);
        }
    } else {
        int* cnt = (int*)d_ws;
        hipMemsetAsync(cnt, 0, cnt_bytes, stream);
        count_rd_kernel<<<(N_EDGES + 255) / 256, 256, 0, stream>>>(ei, et, cnt);
        gemm_kernel<<<512, 256, 0, stream>>>(x, root, bias, nullptr, out, 0);
        edge_transform_kernel<<<65536, CH, 0, stream>>>(ei, et, x, W, cnt, out);
    }
}

// Round 11
// 266.701 us; speedup vs baseline: 1.1217x; 1.0127x over previous
//
#include <hip/hip_runtime.h>
#include <hip/hip_bf16.h>
#include <stdint.h>

#define N_NODES 100000
#define N_EDGES 1600000
#define CH 128
#define N_REL 8
#define N_PAD 100096            // N_NODES rounded up to multiple of 128
#define N_KEYS (N_NODES * N_REL)

#define NBKT 782                // N_PAD / 128 buckets (= fused grid)
#define NCHUNK 782              // edge chunks (one per prep block)
#define CHUNK_E 2048            // edges per chunk (256 thr x 8)
#define OFFS_STRIDE 784         // per-chunk offset row (782 buckets + total + pad)
#define PERM_LDS_CAP 4096       // per-bucket edges ~2046 +- 45 -> 45-sigma margin

using frag_ab = __attribute__((ext_vector_type(8))) short;  // 8 bf16
using frag_cd = __attribute__((ext_vector_type(4))) float;  // 4 fp32

__device__ __forceinline__ short f2bs(float f) {
    union { __hip_bfloat16 h; short s; } u;
    u.h = __float2bfloat16(f);
    return u.s;
}

__device__ __forceinline__ uint32_t pack2bf(float a, float b) {
    union { __hip_bfloat16 h; unsigned short s; } ua, ub;
    ua.h = __float2bfloat16(a); ub.h = __float2bfloat16(b);
    return (uint32_t)ua.s | ((uint32_t)ub.s << 16);
}

__device__ __forceinline__ float bf_lo(uint32_t u) { return __uint_as_float(u << 16); }
__device__ __forceinline__ float bf_hi(uint32_t u) { return __uint_as_float(u & 0xffff0000u); }

// ======================= prep: compact per-chunk CSR (+xconv +bconv) =======================
// R11: xconv rides here (prep's LDS is 24KB -> ~6 blocks/CU, high occupancy --
// unlike R8's 62.5KB mistake). Pass 1 packs entries to LDS + counts; 256-wide
// scan -> exclusive offsets (offs[c][784]); pass 2 compacts in LDS; linear 8KB
// uint4 writeout. Entry: src<<10 | (dst&127)<<3 | rel. Zero global atomics.

__global__ __launch_bounds__(256)
void prep_kernel(const int* __restrict__ ei, const int* __restrict__ et,
                 uint32_t* __restrict__ ents, int* __restrict__ offs,
                 const float* __restrict__ x, short* __restrict__ xb,
                 const float* __restrict__ root, const float* __restrict__ W,
                 short* __restrict__ Bsw) {
    __shared__ uint32_t esave[CHUNK_E];   // 8 KB: packed entries, arrival order
    __shared__ uint32_t csave[CHUNK_E];   // 8 KB: compact (bucket-sorted) entries
    __shared__ short bsave[CHUNK_E];      // 4 KB: bucket id per entry (-1 invalid)
    __shared__ int cnt[NBKT];             // count -> cursor
    __shared__ int scan_t[256];
    const int tid = threadIdx.x;
    const int c = blockIdx.x;
    const int g = blockIdx.x * 256 + tid;

    // --- bconv rides on blocks 0..71 ---
    if (g < 9 * 2048) {
        int chunk = g >> 11, entry = g & 2047;
        int m16 = entry & 15, ct = (entry >> 4) & 7, quad = (entry >> 7) & 3, ks = entry >> 9;
        const float* src = (chunk == 0) ? root : W + (size_t)(chunk - 1) * CH * CH;
        int col = ct * 16 + m16, kb = ks * 32 + quad * 8;
        frag_ab f;
#pragma unroll
        for (int j = 0; j < 8; ++j) f[j] = f2bs(src[(size_t)(kb + j) * CH + col]);
        *(frag_ab*)(Bsw + (size_t)g * 8) = f;
    }

    // --- xconv grid-stride: x fp32 -> bf16 (8 iters/thread over 782x256 grid) ---
    {
        const int nst = NCHUNK * 256;
        const float4* xp = (const float4*)x;
        for (int gi = g; gi < N_NODES * CH / 8; gi += nst) {
            float4 a = xp[(size_t)gi * 2], bb = xp[(size_t)gi * 2 + 1];
            frag_ab f;
            f[0] = f2bs(a.x); f[1] = f2bs(a.y); f[2] = f2bs(a.z); f[3] = f2bs(a.w);
            f[4] = f2bs(bb.x); f[5] = f2bs(bb.y); f[6] = f2bs(bb.z); f[7] = f2bs(bb.w);
            *(frag_ab*)(xb + (size_t)gi * 8) = f;
        }
    }

    for (int i = tid; i < NBKT; i += 256) cnt[i] = 0;
    __syncthreads();
    // --- pass 1: read edges (coalesced), pack to LDS, count per bucket ---
#pragma unroll
    for (int j = 0; j < 8; ++j) {
        const int li = j * 256 + tid;
        const int e = c * CHUNK_E + li;
        if (e < N_EDGES) {
            const int dst = ei[N_EDGES + e];
            const int src = ei[e];
            const int r = et[e];
            const int b = dst >> 7;
            atomicAdd(&cnt[b], 1);
            esave[li] = ((uint32_t)src << 10) | ((uint32_t)(dst & 127) << 3) | (uint32_t)r;
            bsave[li] = (short)b;
        } else {
            bsave[li] = -1;
        }
    }
    __syncthreads();
    // --- scan cnt[0..781] -> exclusive offsets (thread t owns 4t..4t+3) ---
    const int b4 = 4 * tid;
    int c0 = (b4 < NBKT) ? cnt[b4] : 0;
    int c1 = (b4 + 1 < NBKT) ? cnt[b4 + 1] : 0;
    int c2 = (b4 + 2 < NBKT) ? cnt[b4 + 2] : 0;
    int c3 = (b4 + 3 < NBKT) ? cnt[b4 + 3] : 0;
    const int s4 = c0 + c1 + c2 + c3;
    scan_t[tid] = s4;
    __syncthreads();
    for (int st = 1; st < 256; st <<= 1) {    // Hillis-Steele inclusive
        int u = (tid >= st) ? scan_t[tid - st] : 0;
        __syncthreads();
        scan_t[tid] += u;
        __syncthreads();
    }
    const int excl = scan_t[tid] - s4;
    const int total = scan_t[255];
    {
        const int o0 = excl, o1 = o0 + c0, o2 = o1 + c1, o3 = o2 + c2;
        int* og = offs + (size_t)c * OFFS_STRIDE;
        if (b4 < NBKT)     { cnt[b4]     = o0; og[b4]     = o0; }
        if (b4 + 1 < NBKT) { cnt[b4 + 1] = o1; og[b4 + 1] = o1; }
        if (b4 + 2 < NBKT) { cnt[b4 + 2] = o2; og[b4 + 2] = o2; }
        if (b4 + 3 < NBKT) { cnt[b4 + 3] = o3; og[b4 + 3] = o3; }
        if (tid == 0) og[NBKT] = total;
    }
    __syncthreads();
    // --- pass 2: place entries at compact positions ---
#pragma unroll
    for (int j = 0; j < 8; ++j) {
        const int li = j * 256 + tid;
        const int b = bsave[li];
        if (b >= 0) {
            const int pos = atomicAdd(&cnt[b], 1);
            csave[pos] = esave[li];
        }
    }
    __syncthreads();
    // --- linear writeout: 8 KB as uint4 (2 iters/thread) ---
    {
        const uint4* cs = (const uint4*)csave;
        uint4* dg = (uint4*)(ents + (size_t)c * CHUNK_E);
#pragma unroll
        for (int i = 0; i < 2; ++i) dg[tid + 256 * i] = cs[tid + 256 * i];
    }
}

// ======================= FUSED: slice-copy + bin + aggregate + GEMM =======================
// R11: bin folded in (dense compact-CSR form only -- NOT R7's sparse-slot
// scan). Block b: slice bounds from offs (L2-shared x16 siblings), pair-scan
// -> stage bases, dense slice copy into stage[] (aliases A-tile), hist/scan/
// scatter directly into perm_lds. Kills the 32MB perm/ends round-trip + one
// launch. Root MFMA overlaps the scatter tail. Relation loop unchanged
// (133us structure): 4-lane groups, 64B/lane, unroll x2, swizzled A-tile.
#define ACC_U4(U, B)                                            \
    do {                                                        \
        a[(B)+0] += bf_lo((U).x); a[(B)+1] += bf_hi((U).x);     \
        a[(B)+2] += bf_lo((U).y); a[(B)+3] += bf_hi((U).y);     \
        a[(B)+4] += bf_lo((U).z); a[(B)+5] += bf_hi((U).z);     \
        a[(B)+6] += bf_lo((U).w); a[(B)+7] += bf_hi((U).w);     \
    } while (0)

__global__ __launch_bounds__(512, 4)
void rgcn_fused(const uint32_t* __restrict__ ents, const int* __restrict__ offs,
                const short* __restrict__ xb, const short* __restrict__ Bsw,
                const float* __restrict__ bias, float* __restrict__ out) {
    __shared__ short Ash[128 * 128];        // 32 KB A-tile; aliased in binning
    __shared__ int perm_lds[PERM_LDS_CAP];  // 16 KB
    __shared__ int lends[1025];             // local ends; lends[0] = 0
    __shared__ int soff[NCHUNK];            // 3.1 KB slice start per chunk
    __shared__ int slen[NCHUNK];            // 3.1 KB slice len per chunk
    __shared__ int sbase[NCHUNK];           // 3.1 KB stage base per chunk
    uint32_t* stage  = (uint32_t*)Ash;      // [4096] 16 KB  (alias)
    int*      hist   = (int*)Ash + 4096;    // [1024]  4 KB  (alias)
    int*      cursor = (int*)Ash + 5120;    // [1024]  4 KB  (alias)
    int*      shl    = (int*)Ash + 6144;    // [512]   2 KB  (alias)

    const int tid = threadIdx.x;
    const int wave = tid >> 6, lane = tid & 63;
    const int m16 = lane & 15, quad = lane >> 4;
    const int wm = wave >> 2, wn = wave & 3;     // wave tile: 64 rows x 32 cols
    const int b = blockIdx.x;
    const long B0 = (long)b * 128;

    // ---- P0: slice bounds (offs lines shared by 16 sibling buckets) ----
    for (int c = tid; c < NCHUNK; c += 512) {
        const int s = offs[(size_t)c * OFFS_STRIDE + b];
        const int e = offs[(size_t)c * OFFS_STRIDE + b + 1];
        soff[c] = s;
        slen[c] = e - s;
    }
    hist[tid] = 0; hist[tid + 512] = 0;
    if (tid == 0) perm_lds[0] = 0;          // safe gather target for empty segs
    __syncthreads();
    // ---- P1: pair-scan slice lengths -> per-chunk stage base ----
    int n_tot;
    {
        const int t2 = 2 * tid;
        const int l0 = (t2 < NCHUNK) ? slen[t2] : 0;
        const int l1 = (t2 + 1 < NCHUNK) ? slen[t2 + 1] : 0;
        const int ls = l0 + l1;
        shl[tid] = ls;
        __syncthreads();
        for (int st = 1; st < 512; st <<= 1) {
            int u = (tid >= st) ? shl[tid - st] : 0;
            __syncthreads();
            shl[tid] += u;
            __syncthreads();
        }
        const int lexcl = shl[tid] - ls;
        if (t2 < NCHUNK)     sbase[t2]     = lexcl;
        if (t2 + 1 < NCHUNK) sbase[t2 + 1] = lexcl + l0;
        __syncthreads();
        n_tot = shl[511];
        if (n_tot > PERM_LDS_CAP) n_tot = PERM_LDS_CAP;
    }
    // ---- P2: dense slice copy into stage (thread t owns chunks 2t, 2t+1) ----
#pragma unroll
    for (int k = 0; k < 2; ++k) {
        const int c = 2 * tid + k;
        if (c < NCHUNK) {
            const int s = soff[c], nc = slen[c], base = sbase[c];
            const uint32_t* srcp = ents + (size_t)c * CHUNK_E + s;
            for (int i = 0; i < nc; ++i) {
                const int pos = base + i;
                if (pos < PERM_LDS_CAP) stage[pos] = srcp[i];
            }
        }
    }
    __syncthreads();
    // ---- P3: hist over compact entries (key = (dst&127)*8 + rel) ----
    for (int i = tid; i < n_tot; i += 512) atomicAdd(&hist[stage[i] & 1023], 1);
    __syncthreads();
    // ---- P4: scan hist -> cursor + local segment ends ----
    {
        const int h0 = hist[2 * tid], h1 = hist[2 * tid + 1];
        const int s2 = h0 + h1;
        shl[tid] = s2;
        __syncthreads();
        for (int st = 1; st < 512; st <<= 1) {
            int u = (tid >= st) ? shl[tid - st] : 0;
            __syncthreads();
            shl[tid] += u;
            __syncthreads();
        }
        const int excl = shl[tid] - s2;
        cursor[2 * tid]     = excl;
        cursor[2 * tid + 1] = excl + h0;
        if (tid == 0) lends[0] = 0;
        int e1 = excl + h0, e2 = excl + h0 + h1;
        lends[1 + 2 * tid] = (e1 > PERM_LDS_CAP) ? PERM_LDS_CAP : e1;
        lends[2 + 2 * tid] = (e2 > PERM_LDS_CAP) ? PERM_LDS_CAP : e2;
    }
    __syncthreads();
    // ---- P5: scatter stage -> perm_lds (src ids, key-sorted) ----
    for (int i = tid; i < n_tot; i += 512) {
        const uint32_t v = stage[i];
        const int pos = atomicAdd(&cursor[v & 1023], 1);
        if (pos < PERM_LDS_CAP) perm_lds[pos] = (int)(v >> 10);
    }

    // ---- chunk 0 (root): A direct from global xb; overlaps the scatter tail ----
    float bcol[2];
#pragma unroll
    for (int ct = 0; ct < 2; ++ct) bcol[ct] = bias[wn * 32 + ct * 16 + m16];

    frag_cd acc[4][2];
#pragma unroll
    for (int mt = 0; mt < 4; ++mt)
#pragma unroll
        for (int ct = 0; ct < 2; ++ct) acc[mt][ct] = (frag_cd){0.f, 0.f, 0.f, 0.f};

#pragma unroll
    for (int ks = 0; ks < 4; ++ks) {
        frag_ab af[4];
#pragma unroll
        for (int mt = 0; mt < 4; ++mt)
            af[mt] = *(const frag_ab*)(xb + (B0 + wm * 64 + mt * 16 + m16) * CH + ks * 32 + quad * 8);
#pragma unroll
        for (int ct = 0; ct < 2; ++ct) {
            frag_ab bf = *(const frag_ab*)(Bsw + (size_t)((((ks * 4 + quad) * 8) + wn * 2 + ct) * 16 + m16) * 8);
#pragma unroll
            for (int mt = 0; mt < 4; ++mt)
                acc[mt][ct] = __builtin_amdgcn_mfma_f32_16x16x32_bf16(af[mt], bf, acc[mt][ct], 0, 0, 0);
        }
    }
    __syncthreads();   // binning aliases dead, perm_lds/lends ready, Ash free

    // ---- relation loop ----
    const int lrow = tid >> 2;                     // 4-lane group -> one dst row
    const int q4 = tid & 3;
    const uint32_t ch64 = (uint32_t)q4 << 6;       // this lane's 64B channel slice
    const char* xbp = (const char*)xb;
    char* drow = (char*)Ash + lrow * 256;
    const int swz = lrow & 7;

    for (int r = 0; r < N_REL; ++r) {
        const int keyL = lrow * 8 + r;
        const int s = lends[keyL];
        const int e = lends[keyL + 1];
        float a[32];
#pragma unroll
        for (int i = 0; i < 32; ++i) a[i] = 0.f;
        int p0 = perm_lds[(s < e) ? s : 0];
        int p1 = perm_lds[(s + 1 < e) ? s + 1 : ((s < e) ? s : 0)];
        for (int k = s; k < e; k += 2) {
            const char* c0 = xbp + (((size_t)(uint32_t)p0 << 8) | ch64);
            const char* c1 = xbp + (((size_t)(uint32_t)p1 << 8) | ch64);
            const uint4 u0 = *(const uint4*)(c0);
            const uint4 u1 = *(const uint4*)(c0 + 16);
            const uint4 u2 = *(const uint4*)(c0 + 32);
            const uint4 u3 = *(const uint4*)(c0 + 48);
            const uint4 u4 = *(const uint4*)(c1);
            const uint4 u5 = *(const uint4*)(c1 + 16);
            const uint4 u6 = *(const uint4*)(c1 + 32);
            const uint4 u7 = *(const uint4*)(c1 + 48);
            const bool two = (k + 1 < e);
            const int kn = k + 2;
            p0 = perm_lds[(kn < e) ? kn : 0];
            p1 = perm_lds[(kn + 1 < e) ? kn + 1 : 0];
            ACC_U4(u0, 0); ACC_U4(u1, 8); ACC_U4(u2, 16); ACC_U4(u3, 24);
            if (two) { ACC_U4(u4, 0); ACC_U4(u5, 8); ACC_U4(u6, 16); ACC_U4(u7, 24); }
        }
        const int c = e - s;
        const float sc = (c > 1) ? (1.0f / (float)c) : 1.0f;
#pragma unroll
        for (int t = 0; t < 4; ++t) {
            uint4 w;
            w.x = pack2bf(a[t * 8 + 0] * sc, a[t * 8 + 1] * sc);
            w.y = pack2bf(a[t * 8 + 2] * sc, a[t * 8 + 3] * sc);
            w.z = pack2bf(a[t * 8 + 4] * sc, a[t * 8 + 5] * sc);
            w.w = pack2bf(a[t * 8 + 6] * sc, a[t * 8 + 7] * sc);
            *(uint4*)(drow + (((q4 * 4 + t) ^ swz) << 4)) = w;   // swizzled A-tile write
        }
        __syncthreads();
        // ---- MFMA chunk r+1: A from LDS (swizzled ds_read_b128), B from L2-hot Bsw ----
        const short* Bc = Bsw + (size_t)(r + 1) * 2048 * 8;
#pragma unroll
        for (int ks = 0; ks < 4; ++ks) {
            frag_ab af[4];
#pragma unroll
            for (int mt = 0; mt < 4; ++mt) {
                const int lr = wm * 64 + mt * 16 + m16;
                af[mt] = *(const frag_ab*)((const char*)Ash + lr * 256 + (((ks * 4 + quad) ^ (lr & 7)) << 4));
            }
#pragma unroll
            for (int ct = 0; ct < 2; ++ct) {
                frag_ab bf = *(const frag_ab*)(Bc + (size_t)((((ks * 4 + quad) * 8) + wn * 2 + ct) * 16 + m16) * 8);
#pragma unroll
                for (int mt = 0; mt < 4; ++mt)
                    acc[mt][ct] = __builtin_amdgcn_mfma_f32_16x16x32_bf16(af[mt], bf, acc[mt][ct], 0, 0, 0);
            }
        }
        __syncthreads();
    }

    // ---- epilogue ----
#pragma unroll
    for (int mt = 0; mt < 4; ++mt) {
#pragma unroll
        for (int ct = 0; ct < 2; ++ct) {
            const long row0 = B0 + wm * 64 + mt * 16 + quad * 4;
            const int col = wn * 32 + ct * 16 + m16;
#pragma unroll
            for (int rg = 0; rg < 4; ++rg) {
                const long rr = row0 + rg;
                if (rr < N_NODES) out[rr * CH + col] = acc[mt][ct][rg] + bcol[ct];
            }
        }
    }
}

// ======================= fallback tiers (round-1 code) =======================

__global__ void count_rd_kernel(const int* __restrict__ ei, const int* __restrict__ et,
                                int* __restrict__ cnt) {
    int e = blockIdx.x * 256 + threadIdx.x;
    if (e < N_EDGES) {
        int dst = ei[N_EDGES + e];
        int r = et[e];
        atomicAdd(&cnt[r * N_NODES + dst], 1);
    }
}

__global__ void scatter_kernel(const int* __restrict__ ei, const int* __restrict__ et,
                               const float* __restrict__ x, float* __restrict__ sums,
                               int rel) {
    int gid = (blockIdx.x * 256 + threadIdx.x) >> 5;
    int lane = threadIdx.x & 31;
    int ngroups = gridDim.x * 8;
    for (int e = gid; e < N_EDGES; e += ngroups) {
        if (et[e] != rel) continue;
        int src = ei[e];
        int dst = ei[N_EDGES + e];
        float4 v = ((const float4*)(x + (size_t)src * CH))[lane];
        float* s = sums + (size_t)dst * CH + (size_t)lane * 4;
        atomicAdd(s + 0, v.x);
        atomicAdd(s + 1, v.y);
        atomicAdd(s + 2, v.z);
        atomicAdd(s + 3, v.w);
    }
}

__global__ __launch_bounds__(256, 2)
void gemm_kernel(const float* __restrict__ A, const float* __restrict__ B,
                 const float* __restrict__ bias, const int* __restrict__ cnt,
                 float* __restrict__ out, int accumulate) {
    const int wave = threadIdx.x >> 6;
    const int lane = threadIdx.x & 63;
    const int m16 = lane & 15;
    const int quad = lane >> 4;

    frag_ab bfrag[4][8];
#pragma unroll
    for (int ks = 0; ks < 4; ++ks) {
        const int kb = ks * 32 + quad * 8;
#pragma unroll
        for (int ct = 0; ct < 8; ++ct) {
            const int col = ct * 16 + m16;
            frag_ab f;
#pragma unroll
            for (int j = 0; j < 8; ++j)
                f[j] = f2bs(B[(size_t)(kb + j) * CH + col]);
            bfrag[ks][ct] = f;
        }
    }

    const int nstrips = (N_NODES + 63) / 64;
    for (int strip = blockIdx.x; strip < nstrips; strip += gridDim.x) {
        const int row = strip * 64 + wave * 16 + m16;
        const bool valid = row < N_NODES;
        float scale = 1.0f;
        if (cnt != nullptr && valid) {
            int c = cnt[row];
            if (c > 1) scale = 1.0f / (float)c;
        }
        const float4* arow = (const float4*)(A + (size_t)(valid ? row : 0) * CH);
        frag_cd acc[8];
#pragma unroll
        for (int ct = 0; ct < 8; ++ct) acc[ct] = (frag_cd){0.f, 0.f, 0.f, 0.f};
#pragma unroll
        for (int ks = 0; ks < 4; ++ks) {
            float4 a0 = arow[ks * 8 + quad * 2];
            float4 a1 = arow[ks * 8 + quad * 2 + 1];
            frag_ab af;
            af[0] = f2bs(a0.x * scale); af[1] = f2bs(a0.y * scale);
            af[2] = f2bs(a0.z * scale); af[3] = f2bs(a0.w * scale);
            af[4] = f2bs(a1.x * scale); af[5] = f2bs(a1.y * scale);
            af[6] = f2bs(a1.z * scale); af[7] = f2bs(a1.w * scale);
#pragma unroll
            for (int ct = 0; ct < 8; ++ct)
                acc[ct] = __builtin_amdgcn_mfma_f32_16x16x32_bf16(af, bfrag[ks][ct], acc[ct], 0, 0, 0);
        }
        const int obase = strip * 64 + wave * 16 + quad * 4;
#pragma unroll
        for (int ct = 0; ct < 8; ++ct) {
            const int col = ct * 16 + m16;
#pragma unroll
            for (int rg = 0; rg < 4; ++rg) {
                const int r = obase + rg;
                if (r < N_NODES) {
                    const size_t idx = (size_t)r * CH + col;
                    if (accumulate) out[idx] += acc[ct][rg];
                    else out[idx] = acc[ct][rg] + bias[col];
                }
            }
        }
    }
}

__global__ void edge_transform_kernel(const int* __restrict__ ei, const int* __restrict__ et,
                                      const float* __restrict__ x, const float* __restrict__ W,
                                      const int* __restrict__ cnt, float* __restrict__ out) {
    __shared__ float xs[CH];
    const int tid = threadIdx.x;
    for (int e = blockIdx.x; e < N_EDGES; e += gridDim.x) {
        const int src = ei[e];
        const int dst = ei[N_EDGES + e];
        const int r = et[e];
        __syncthreads();
        xs[tid] = x[(size_t)src * CH + tid];
        __syncthreads();
        const int c = cnt[r * N_NODES + dst];
        const float scale = (c > 1) ? (1.0f / (float)c) : 1.0f;
        const float* Wr = W + (size_t)r * CH * CH;
        float acc = 0.f;
#pragma unroll 8
        for (int k = 0; k < CH; ++k) acc += xs[k] * Wr[(size_t)k * CH + tid];
        atomicAdd(&out[(size_t)dst * CH + tid], acc * scale);
    }
}

// ======================= launch =======================

static inline size_t al512(size_t x) { return (x + 511) & ~(size_t)511; }

extern "C" void kernel_launch(void* const* d_in, const int* in_sizes, int n_in,
                              void* d_out, int out_size, void* d_ws, size_t ws_size,
                              hipStream_t stream) {
    const float* x    = (const float*)d_in[0];
    const int*   ei   = (const int*)d_in[1];   // [2, E]: row0=src, row1=dst
    const int*   et   = (const int*)d_in[2];   // [E]
    const float* W    = (const float*)d_in[3]; // [R,128,128]
    const float* root = (const float*)d_in[4]; // [128,128]
    const float* bias = (const float*)d_in[5]; // [128]
    float* out = (float*)d_out;

    // ---- tier-1 workspace layout (compact per-chunk CSR, 2-kernel pipeline) ----
    size_t o = 0;
    const size_t o_ents = o; o += al512((size_t)NCHUNK * CHUNK_E * 4);        // 6.4 MB
    const size_t o_offs = o; o += al512((size_t)NCHUNK * OFFS_STRIDE * 4);    // 2.45 MB
    const size_t o_bsw  = o; o += al512((size_t)9 * 2048 * 16);
    const size_t o_xb   = o; o += al512((size_t)N_PAD * CH * 2);              // 25.6 MB
    const size_t need_t1 = o;

    const size_t cnt_bytes = (size_t)N_REL * N_NODES * sizeof(int);
    const size_t cnt_rsv   = al512(cnt_bytes);
    const size_t sums51    = (size_t)N_NODES * CH * sizeof(float);

    char* ws = (char*)d_ws;
    if (ws_size >= need_t1) {
        uint32_t* ents = (uint32_t*)(ws + o_ents);
        int*      offs = (int*)(ws + o_offs);
        short*    Bsw  = (short*)(ws + o_bsw);
        short*    xb   = (short*)(ws + o_xb);

        prep_kernel<<<NCHUNK, 256, 0, stream>>>(ei, et, ents, offs, x, xb, root, W, Bsw);
        rgcn_fused<<<NBKT, 512, 0, stream>>>(ents, offs, xb, Bsw, bias, out);
    } else if (ws_size >= cnt_rsv + sums51) {
        int*   cnt  = (int*)d_ws;
        float* sums = (float*)((char*)d_ws + cnt_rsv);
        hipMemsetAsync(cnt, 0, cnt_bytes, stream);
        count_rd_kernel<<<(N_EDGES + 255) / 256, 256, 0, stream>>>(ei, et, cnt);
        gemm_kernel<<<512, 256, 0, stream>>>(x, root, bias, nullptr, out, 0);
        for (int r = 0; r < N_REL; ++r) {
            hipMemsetAsync(sums, 0, sums51, stream);
            scatter_kernel<<<6400, 256, 0, stream>>>(ei, et, x, sums, r);
            gemm_kernel<<<512, 256, 0, stream>>>(sums, W + (size_t)r * CH * CH,
                                                 nullptr, cnt + (size_t)r * N_NODES, out, 1);
        }
    } else {
        int* cnt = (int*)d_ws;
        hipMemsetAsync(cnt, 0, cnt_bytes, stream);
        count_rd_kernel<<<(N_EDGES + 255) / 256, 256, 0, stream>>>(ei, et, cnt);
        gemm_kernel<<<512, 256, 0, stream>>>(x, root, bias, nullptr, out, 0);
        edge_transform_kernel<<<65536, CH, 0, stream>>>(ei, et, x, W, cnt, out);
    }
}